// Round 9
// baseline (91.069 us; speedup 1.0000x reference)
//
#include <hip/hip_runtime.h>
#include <math.h>

constexpr int B_ = 256;
constexpr int D_ = 128;
constexpr int N_ = 65536;
constexpr int P_ = 100;
constexpr int K_ = 4096;
constexpr int P2_ = 10;
constexpr int KP_ = K_ + P_;       // 4196
constexpr int OC_ = P2_ + K_;      // 4106
constexpr int NT_ = 1024;          // row-tiles (row>>6), 64 rows each
constexpr int SLOT_ = 1536;        // per-tile list capacity (mean 1024, sd 32)
constexpr int GCOS_ = 256;         // cos blocks   [0, 256)
constexpr int GGEMM_ = 1024;       // gemm blocks  [256, 1280)
constexpr int GCOPY_ = 2048;       // copy blocks  [1280, 3328)
constexpr float T_ = 0.07f;

typedef __attribute__((ext_vector_type(8))) short bf16x8;
typedef __attribute__((ext_vector_type(4))) float f32x4v;

// ---- kernel P: split v2 into bf16 hi/lo; block 32 zeroes gcount ----
__global__ __launch_bounds__(256) void k_prep(
    const float* __restrict__ v2, unsigned short* __restrict__ v2h,
    unsigned short* __restrict__ v2l, int* __restrict__ gcount)
{
  const int tid = threadIdx.x;
  if (blockIdx.x == 32) {                          // zero the 1024 tile counters
    gcount[tid] = 0;
    gcount[tid + 256] = 0;
    gcount[tid + 512] = 0;
    gcount[tid + 768] = 0;
    return;
  }
  const int i4 = blockIdx.x * 256 + tid;           // 8192 float4 total
  const float4 v = reinterpret_cast<const float4*>(v2)[i4];
  const float f[4] = {v.x, v.y, v.z, v.w};
  unsigned short h[4], l[4];
#pragma unroll
  for (int j = 0; j < 4; ++j) {
    const unsigned u = __float_as_uint(f[j]);
    h[j] = (unsigned short)(u >> 16);
    const float al = f[j] - __uint_as_float(u & 0xFFFF0000u);
    l[j] = (unsigned short)(__float_as_uint(al) >> 16);
  }
  ushort4 hv = {h[0], h[1], h[2], h[3]};
  ushort4 lv = {l[0], l[1], l[2], l[3]};
  reinterpret_cast<ushort4*>(v2h)[i4] = hv;
  reinterpret_cast<ushort4*>(v2l)[i4] = lv;
}

// ---- kernel B: bin (b,k) entries by 64-row tile ----
// entry u32 = (rowlocal 6b << 20) | (b 8b << 12) | (k 12b)
__global__ __launch_bounds__(256) void k_bin(
    const int* __restrict__ idx, unsigned* __restrict__ lists,
    int* __restrict__ gcount)
{
  const int b = blockIdx.x;
  const int tid = threadIdx.x;
  __shared__ int cnt[NT_];
  __shared__ int gbase[NT_];
  for (int t = tid; t < NT_; t += 256) cnt[t] = 0;
  __syncthreads();
  const int4* __restrict__ src = reinterpret_cast<const int4*>(idx + (size_t)b * KP_ + P_);
  unsigned short rows[16];
#pragma unroll
  for (int q = 0; q < 4; ++q) {
    const int4 r = src[q * 256 + tid];
    rows[q * 4 + 0] = (unsigned short)r.x;
    rows[q * 4 + 1] = (unsigned short)r.y;
    rows[q * 4 + 2] = (unsigned short)r.z;
    rows[q * 4 + 3] = (unsigned short)r.w;
    atomicAdd(&cnt[r.x >> 6], 1);
    atomicAdd(&cnt[r.y >> 6], 1);
    atomicAdd(&cnt[r.z >> 6], 1);
    atomicAdd(&cnt[r.w >> 6], 1);
  }
  __syncthreads();
  for (int t = tid; t < NT_; t += 256) {
    const int c = cnt[t];
    gbase[t] = c ? atomicAdd(&gcount[t], c) : 0;
  }
  __syncthreads();
  for (int t = tid; t < NT_; t += 256) cnt[t] = 0;   // reuse as cursor
  __syncthreads();
#pragma unroll
  for (int q = 0; q < 4; ++q) {
#pragma unroll
    for (int u = 0; u < 4; ++u) {
      const int row = rows[q * 4 + u];
      const int tile = row >> 6;
      const int off = atomicAdd(&cnt[tile], 1);
      const int pos = gbase[tile] + off;
      if (pos < SLOT_)
        lists[(size_t)tile * SLOT_ + pos] =
            ((unsigned)(row & 63) << 20) | ((unsigned)b << 12) |
            (unsigned)((q * 256 + tid) * 4 + u);
    }
  }
}

__device__ inline void split8(const f32x4v lo, const f32x4v hi,
                              bf16x8& h, bf16x8& l) {
#pragma unroll
  for (int j = 0; j < 4; ++j) {
    const unsigned u = __float_as_uint(lo[j]);
    h[j] = (short)(u >> 16);
    const float al = lo[j] - __uint_as_float(u & 0xFFFF0000u);
    l[j] = (short)(__float_as_uint(al) >> 16);
  }
#pragma unroll
  for (int j = 0; j < 4; ++j) {
    const unsigned u = __float_as_uint(hi[j]);
    h[4 + j] = (short)(u >> 16);
    const float al = hi[j] - __uint_as_float(u & 0xFFFF0000u);
    l[4 + j] = (short)(__float_as_uint(al) >> 16);
  }
}

// ---- kernel M: [0,256) cos+select; [256,1280) GEMM(64row x 256b)+fused
//                exp/scatter epilogue; [1280,3328) copy mem1 -> outmem ----
__global__ __launch_bounds__(512, 4) void k_mega(
    const float* __restrict__ v1, const float* __restrict__ v2,
    const int* __restrict__ idx, const float* __restrict__ mem1,
    const float* __restrict__ mem2, const unsigned short* __restrict__ v2h,
    const unsigned short* __restrict__ v2l, const unsigned* __restrict__ lists,
    const int* __restrict__ gcount, float* __restrict__ out,
    float* __restrict__ outmem, double* __restrict__ wpart)
{
  const int tid = threadIdx.x;
  const unsigned bid = blockIdx.x;
  __shared__ char smem[65792];       // gemm: eL [64][257] f32 | cos: aliased
  __shared__ double lacc8[8];

  if (bid < GCOS_) {
    // ================= cosine path (r < P) + stable top-10 =================
    float* sbuf = (float*)smem;                      // 2*D floats
    double* sdiff = (double*)(smem + 1024);          // P doubles
    float* swout = (float*)(smem + 1024 + 800);      // P floats
    double* dsn2 = (double*)(smem + 1024 + 800 + 416);
    double* dss = (double*)(smem + 1024 + 800 + 416 + 800);
    double* dinv = (double*)(smem + 1024 + 800 + 416 + 1600);
    const int b = bid;
    if (tid < 32)
      reinterpret_cast<float4*>(sbuf)[tid] =
          reinterpret_cast<const float4*>(v2 + (size_t)b * D_)[tid];
    else if (tid < 64)
      reinterpret_cast<float4*>(sbuf)[tid] =
          reinterpret_cast<const float4*>(v1 + (size_t)b * D_)[tid - 32];
    __syncthreads();
    if (tid < 64) {
      const float2* s2 = reinterpret_cast<const float2*>(sbuf);
      const float2 a = s2[tid];
      const float2 c = s2[64 + tid];
      double dn2 = (double)a.x * a.x + (double)a.y * a.y;
      double dn1 = (double)c.x * c.x + (double)c.y * c.y;
#pragma unroll
      for (int sh = 1; sh < 64; sh <<= 1) {
        dn2 += __shfl_xor(dn2, sh);
        dn1 += __shfl_xor(dn1, sh);
      }
      if (tid == 0) { dinv[0] = 1.0 / sqrt(dn1); dinv[1] = 1.0 / sqrt(dn2); }
    }
    if (tid >= 128 && tid < 128 + P_) {
      const int r = tid - 128;
      const int row = idx[(size_t)b * KP_ + r];
      const float4* __restrict__ w2p = reinterpret_cast<const float4*>(mem2 + (size_t)row * D_);
      const float4* __restrict__ x2p = reinterpret_cast<const float4*>(sbuf);
      double sn2 = 0, ss = 0;
#pragma unroll 4
      for (int jj = 0; jj < 32; ++jj) {
        const float4 cc = w2p[jj];
        const float4 y2 = x2p[jj];
        sn2 += (double)cc.x * cc.x + (double)cc.y * cc.y + (double)cc.z * cc.z + (double)cc.w * cc.w;
        ss  += (double)cc.x * y2.x + (double)cc.y * y2.y + (double)cc.z * y2.z + (double)cc.w * y2.w;
      }
      dsn2[r] = sn2; dss[r] = ss;
    }
    double so = 0, sn1 = 0, st = 0;
    if (tid < P_) {
      const int row = idx[(size_t)b * KP_ + tid];
      const float4* __restrict__ w1p = reinterpret_cast<const float4*>(mem1 + (size_t)row * D_);
      const float4* __restrict__ x2p = reinterpret_cast<const float4*>(sbuf);
      const float4* __restrict__ x1p = reinterpret_cast<const float4*>(sbuf + D_);
#pragma unroll 4
      for (int jj = 0; jj < 32; ++jj) {
        const float4 a  = w1p[jj];
        const float4 y1 = x1p[jj];
        const float4 y2 = x2p[jj];
        so  += (double)a.x * y2.x + (double)a.y * y2.y + (double)a.z * y2.z + (double)a.w * y2.w;
        sn1 += (double)a.x * a.x  + (double)a.y * a.y  + (double)a.z * a.z  + (double)a.w * a.w;
        st  += (double)a.x * y1.x + (double)a.y * y1.y + (double)a.z * y1.z + (double)a.w * y1.w;
      }
    }
    __syncthreads();
    if (tid < P_) {
      const double t_rel = st * dinv[0] / sqrt(sn1);
      const double s_rel = dss[tid] * dinv[1] / sqrt(dsn2[tid]);
      sdiff[tid] = t_rel - s_rel;
      swout[tid] = expf((float)(so * (1.0 / (double)T_)));
    }
    __syncthreads();
    if (tid < 64) {
      const int l = tid;
      const double va = sdiff[l];
      const double vb = (l < P_ - 64) ? sdiff[l + 64] : -1.0e300;
      bool ta = false, tb2 = (l >= P_ - 64);
      int sel[P2_];
#pragma unroll
      for (int t = 0; t < P2_; ++t) {
        double cv; int cj;
        const bool aok = !ta, bok = !tb2;
        if (aok && (!bok || va >= vb)) { cv = va; cj = l; }
        else if (bok)                  { cv = vb; cj = l + 64; }
        else                           { cv = -1.0e300; cj = 0x7fffffff; }
#pragma unroll
        for (int sh = 1; sh < 64; sh <<= 1) {
          const double ov = __shfl_xor(cv, sh);
          const int    oj = __shfl_xor(cj, sh);
          if (ov > cv || (ov == cv && oj < cj)) { cv = ov; cj = oj; }
        }
        sel[t] = cj;
        if (cj == l) ta = true;
        if (cj == l + 64) tb2 = true;
      }
      if (l == 0) {
        sel[0] = 0;  // .at[:,0].set(0) applied AFTER taking top-P2
        double sp = 0.0;
#pragma unroll
        for (int t = 0; t < P2_; ++t) {
          const float e = swout[sel[t]];
          out[(size_t)b * OC_ + t] = e;  // unnormalized
          sp += (double)e;
        }
        wpart[GGEMM_ + b] = sp;
      }
    }
  } else if (bid < GCOS_ + GGEMM_) {
    // ================= GEMM 64 rows x 256 b + fused epilogue =================
    const int tile = bid - GCOS_;
    const int r0 = tile * 64;
    const int wid = tid >> 6, lane = tid & 63;
    const int mb = (wid >> 1) * 64;                // b-offset of wave tile
    const int nb = (wid & 1) * 32;                 // row-offset of wave tile
    const int klane8 = (lane >> 4) * 8;
    f32x4v acc[4][2];
#pragma unroll
    for (int m = 0; m < 4; ++m)
#pragma unroll
      for (int n = 0; n < 2; ++n) acc[m][n] = {0.f, 0.f, 0.f, 0.f};

#pragma unroll
    for (int kk = 0; kk < 4; ++kk) {
      const int ks = kk * 32;
      bf16x8 ah[4], al[4];
#pragma unroll
      for (int m = 0; m < 4; ++m) {
        const size_t o = (size_t)(mb + m * 16 + (lane & 15)) * D_ + ks + klane8;
        ah[m] = *reinterpret_cast<const bf16x8*>(v2h + o);
        al[m] = *reinterpret_cast<const bf16x8*>(v2l + o);
      }
#pragma unroll
      for (int n = 0; n < 2; ++n) {
        const int row = r0 + nb + n * 16 + (lane & 15);
        const float* __restrict__ bp = mem1 + (size_t)row * D_ + ks + klane8;
        const f32x4v p0 = *reinterpret_cast<const f32x4v*>(bp);
        const f32x4v p1 = *reinterpret_cast<const f32x4v*>(bp + 4);
        bf16x8 bh, bl;
        split8(p0, p1, bh, bl);
#pragma unroll
        for (int m = 0; m < 4; ++m) {
          acc[m][n] = __builtin_amdgcn_mfma_f32_16x16x32_bf16(ah[m], bh, acc[m][n], 0, 0, 0);
          acc[m][n] = __builtin_amdgcn_mfma_f32_16x16x32_bf16(ah[m], bl, acc[m][n], 0, 0, 0);
          acc[m][n] = __builtin_amdgcn_mfma_f32_16x16x32_bf16(al[m], bh, acc[m][n], 0, 0, 0);
        }
      }
    }
    // -------- epilogue: regs -> LDS [64][257] -> exp -> scatter --------
    float* eL = (float*)smem;
#pragma unroll
    for (int m = 0; m < 4; ++m)
#pragma unroll
      for (int n = 0; n < 2; ++n) {
        const int rowloc = nb + n * 16 + (lane & 15);
        const int bloc = mb + m * 16 + (lane >> 4) * 4;
#pragma unroll
        for (int reg = 0; reg < 4; ++reg)
          eL[rowloc * 257 + bloc + reg] = acc[m][n][reg];
      }
    __syncthreads();
    const int cntT = min(gcount[tile], SLOT_);
    const unsigned* __restrict__ lb = lists + (size_t)tile * SLOT_;
    double de = 0.0;
    for (int i = tid; i < cntT; i += 512) {
      const unsigned e = lb[i];
      const int rl = e >> 20;
      const int bb = (e >> 12) & 255;
      const int k = e & 4095;
      const float ex = expf(eL[rl * 257 + bb] * (1.0f / T_));
      out[(size_t)bb * OC_ + P2_ + k] = ex;          // unnormalized
      de += (double)ex;
    }
#pragma unroll
    for (int sh = 1; sh < 64; sh <<= 1) de += __shfl_xor(de, sh);
    if (lane == 0) lacc8[wid] = de;
    __syncthreads();
    if (tid == 0) {
      double s = 0.0;
#pragma unroll
      for (int w = 0; w < 8; ++w) s += lacc8[w];
      wpart[tile] = s;
    }
  } else {
    // ================= copy memory_v1 -> outmem =================
    const int g = bid - GCOS_ - GGEMM_;             // 2048 blocks x 1024 float4
    const float4* __restrict__ s4 = reinterpret_cast<const float4*>(mem1) + (size_t)g * 1024;
    float4* __restrict__ d4 = reinterpret_cast<float4*>(outmem) + (size_t)g * 1024;
    d4[tid] = s4[tid];
    d4[tid + 512] = s4[tid + 512];
  }
}

// ---------------- kernel Z: reduce partials -> 1/Z ----------------
__global__ __launch_bounds__(256) void k_z(
    const double* __restrict__ wpart, float* __restrict__ invz)
{
  __shared__ double lds[4];
  const int tid = threadIdx.x;
  double s = 0.0;
  for (int i = tid; i < GGEMM_ + B_; i += 256) s += wpart[i];
#pragma unroll
  for (int sh = 1; sh < 64; sh <<= 1) s += __shfl_xor(s, sh);
  if ((tid & 63) == 0) lds[tid >> 6] = s;
  __syncthreads();
  if (tid == 0) {
    const double S = (lds[0] + lds[1]) + (lds[2] + lds[3]);
    const double Z = S / ((double)B_ * (double)OC_) * (double)N_;
    *invz = (float)(1.0 / Z);
  }
}

// ---------------- kernel S: scale scores by 1/Z + y-row update ----------
constexpr int NSC_ = (B_ * OC_ / 4 + 255) / 256;  // 1027 scale blocks
__global__ __launch_bounds__(256) void k_scale_upd(
    float* __restrict__ out, const float* __restrict__ invz,
    const float* __restrict__ mem1, const float* __restrict__ v1,
    const int* __restrict__ y, float* __restrict__ dst)
{
  const int tid = threadIdx.x;
  if (blockIdx.x < NSC_) {
    const size_t i = (size_t)blockIdx.x * 256 + tid;
    constexpr size_t n4 = (size_t)B_ * OC_ / 4;
    if (i < n4) {
      const float sc = *invz;
      float4 v = reinterpret_cast<float4*>(out)[i];
      v.x *= sc; v.y *= sc; v.z *= sc; v.w *= sc;
      reinterpret_cast<float4*>(out)[i] = v;
    }
  } else if (tid < 64) {
    const int b = blockIdx.x - NSC_;
    const int row = y[b];
    const float2 m = *reinterpret_cast<const float2*>(mem1 + (size_t)row * D_ + tid * 2);
    const float2 a = *reinterpret_cast<const float2*>(v1 + (size_t)b * D_ + tid * 2);
    float2 l;
    l.x = m.x * 0.5f + a.x * 0.5f;
    l.y = m.y * 0.5f + a.y * 0.5f;
    float n = l.x * l.x + l.y * l.y;
#pragma unroll
    for (int sh = 1; sh < 64; sh <<= 1) n += __shfl_xor(n, sh);
    const float inv = 1.0f / sqrtf(n);
    float2 o;
    o.x = l.x * inv;
    o.y = l.y * inv;
    *reinterpret_cast<float2*>(dst + (size_t)row * D_ + tid * 2) = o;
  }
}

extern "C" void kernel_launch(void* const* d_in, const int* in_sizes, int n_in,
                              void* d_out, int out_size, void* d_ws, size_t ws_size,
                              hipStream_t stream) {
  // setup_inputs order: epoch, v1, v2, y, idx, memory_v1, memory_v2
  const float* v1   = (const float*)d_in[1];
  const float* v2   = (const float*)d_in[2];
  const int*   y    = (const int*)d_in[3];
  const int*   idx  = (const int*)d_in[4];
  const float* mem1 = (const float*)d_in[5];
  const float* mem2 = (const float*)d_in[6];

  float* out    = (float*)d_out;                      // (B, P2+K) scores
  float* outmem = out + (size_t)B_ * OC_;             // (N, D) new memory

  char* ws = (char*)d_ws;
  constexpr size_t LSZ = (size_t)NT_ * SLOT_ * 4;     // 6,291,456 B
  unsigned*       lists  = (unsigned*)ws;
  int*            gcount = (int*)(ws + LSZ);                    // 1024 ints
  unsigned short* v2h    = (unsigned short*)(ws + LSZ + 8192);
  unsigned short* v2l    = (unsigned short*)(ws + LSZ + 8192 + 65536);
  double*         wpart  = (double*)(ws + LSZ + 8192 + 2 * 65536);  // 1280 doubles
  float*          invz   = (float*)(ws + LSZ + 8192 + 2 * 65536 + 16384);

  k_prep<<<33, 256, 0, stream>>>(v2, v2h, v2l, gcount);
  k_bin<<<B_, 256, 0, stream>>>(idx, lists, gcount);
  k_mega<<<GCOS_ + GGEMM_ + GCOPY_, 512, 0, stream>>>(
      v1, v2, idx, mem1, mem2, v2h, v2l, lists, gcount, out, outmem, wpart);
  k_z<<<1, 256, 0, stream>>>(wpart, invz);
  k_scale_upd<<<NSC_ + B_, 256, 0, stream>>>(out, invz, mem1, v1, y, outmem);
}

// Round 10
// 80.212 us; speedup vs baseline: 1.1354x; 1.1354x over previous
//
#include <hip/hip_runtime.h>
#include <math.h>

constexpr int B_ = 256;
constexpr int D_ = 128;
constexpr int N_ = 65536;
constexpr int P_ = 100;
constexpr int K_ = 4096;
constexpr int P2_ = 10;
constexpr int KP_ = K_ + P_;       // 4196
constexpr int OC_ = P2_ + K_;      // 4106
constexpr int NBIN_ = 16;          // row>>12 -> 16 bins of 2 MB (2 per XCD L2)
constexpr int SLOT_ = 384;         // capacity per (b,bin); mean 256, sd 16 -> 8 sd
constexpr int GCOS_ = 256;         // cos+select  [0, 256)
constexpr int GCOPY_ = 2048;       // copy        [256, 2304) -- primes L2 slices
constexpr int GGATH_ = B_ * NBIN_; // gather      [2304, 6400)
constexpr int NPART_ = GGATH_ + B_;
constexpr float T_ = 0.07f;

// ---------------- kernel 0: bin the negatives' indices ----------------
// One block per b: scan idx[b][P..P+K) once (int4 coalesced), pack
// (k<<16)|row into per-(b,bin) lists. bin = row>>12 so bin%8 == XCD of the
// gather block that consumes it (gather bid%8 == bin%8).
__global__ __launch_bounds__(256) void k_bin(
    const int* __restrict__ idx, unsigned* __restrict__ lists,
    int* __restrict__ counts)
{
  const int b = blockIdx.x;
  const int tid = threadIdx.x;
  __shared__ int cnt[NBIN_];
  if (tid < NBIN_) cnt[tid] = 0;
  __syncthreads();
  const int4* __restrict__ src = reinterpret_cast<const int4*>(idx + (size_t)b * KP_ + P_);
#pragma unroll
  for (int i = 0; i < 4; ++i) {
    const int4 r4 = src[i * 256 + tid];
    const int ks = (i * 256 + tid) * 4;
    const int rows[4] = {r4.x, r4.y, r4.z, r4.w};
#pragma unroll
    for (int u = 0; u < 4; ++u) {
      const int row = rows[u];
      const int bin = row >> 12;
      const int slot = atomicAdd(&cnt[bin], 1);
      if (slot < SLOT_)
        lists[((size_t)(b * NBIN_ + bin)) * SLOT_ + slot] =
            ((unsigned)(ks + u) << 16) | (unsigned)row;
    }
  }
  __syncthreads();
  if (tid < NBIN_) counts[b * NBIN_ + tid] = min(cnt[tid], SLOT_);
}

// -------- kernel 1: fused cos/select + copy + binned gather (dense e) -----
__global__ __launch_bounds__(256) void k_main(
    const float* __restrict__ v1, const float* __restrict__ v2,
    const int* __restrict__ idx, const float* __restrict__ mem1,
    const float* __restrict__ mem2, const unsigned* __restrict__ lists,
    const int* __restrict__ counts, float* __restrict__ evals,
    float* __restrict__ wsel, float* __restrict__ outmem,
    double* __restrict__ wpart)
{
  const int tid = threadIdx.x;
  const unsigned bid = blockIdx.x;
  __shared__ double lacc[4];
  __shared__ float sbuf[2 * D_];
  __shared__ double sdiff[P_];
  __shared__ float swout[P_];
  __shared__ double dsn2[P_], dss[P_];
  __shared__ double dinv[2];

  if (bid < GCOS_) {
    // ---- cosine path: w1-dots on tid<100, w2-dots on tid in [128,228) ----
    const int b = bid;
    if (tid < 32)
      reinterpret_cast<float4*>(sbuf)[tid] =             // sbuf[0..127] = v2[b]
          reinterpret_cast<const float4*>(v2 + (size_t)b * D_)[tid];
    else if (tid < 64)
      reinterpret_cast<float4*>(sbuf)[tid] =             // sbuf[128..255] = v1[b]
          reinterpret_cast<const float4*>(v1 + (size_t)b * D_)[tid - 32];
    __syncthreads();
    if (tid < 64) {                                      // wave-parallel norms
      const float2* s2 = reinterpret_cast<const float2*>(sbuf);
      const float2 a = s2[tid];        // v2 elems
      const float2 c = s2[64 + tid];   // v1 elems
      double dn2 = (double)a.x * a.x + (double)a.y * a.y;
      double dn1 = (double)c.x * c.x + (double)c.y * c.y;
#pragma unroll
      for (int sh = 1; sh < 64; sh <<= 1) {
        dn2 += __shfl_xor(dn2, sh);
        dn1 += __shfl_xor(dn1, sh);
      }
      if (tid == 0) { dinv[0] = 1.0 / sqrt(dn1); dinv[1] = 1.0 / sqrt(dn2); }
    }
    if (tid >= 128 && tid < 128 + P_) {                  // w2: sn2, ss
      const int r = tid - 128;
      const int row = idx[(size_t)b * KP_ + r];
      const float4* __restrict__ w2p = reinterpret_cast<const float4*>(mem2 + (size_t)row * D_);
      const float4* __restrict__ x2p = reinterpret_cast<const float4*>(sbuf);
      double sn2 = 0, ss = 0;
#pragma unroll 4
      for (int jj = 0; jj < 32; ++jj) {
        const float4 cc = w2p[jj];
        const float4 y2 = x2p[jj];
        sn2 += (double)cc.x * cc.x + (double)cc.y * cc.y + (double)cc.z * cc.z + (double)cc.w * cc.w;
        ss  += (double)cc.x * y2.x + (double)cc.y * y2.y + (double)cc.z * y2.z + (double)cc.w * y2.w;
      }
      dsn2[r] = sn2; dss[r] = ss;
    }
    double so = 0, sn1 = 0, st = 0;
    if (tid < P_) {                                      // w1: so, sn1, st
      const int row = idx[(size_t)b * KP_ + tid];
      const float4* __restrict__ w1p = reinterpret_cast<const float4*>(mem1 + (size_t)row * D_);
      const float4* __restrict__ x2p = reinterpret_cast<const float4*>(sbuf);
      const float4* __restrict__ x1p = reinterpret_cast<const float4*>(sbuf + D_);
#pragma unroll 4
      for (int jj = 0; jj < 32; ++jj) {
        const float4 a  = w1p[jj];
        const float4 y1 = x1p[jj];
        const float4 y2 = x2p[jj];
        so  += (double)a.x * y2.x + (double)a.y * y2.y + (double)a.z * y2.z + (double)a.w * y2.w;
        sn1 += (double)a.x * a.x  + (double)a.y * a.y  + (double)a.z * a.z  + (double)a.w * a.w;
        st  += (double)a.x * y1.x + (double)a.y * y1.y + (double)a.z * y1.z + (double)a.w * y1.w;
      }
    }
    __syncthreads();
    if (tid < P_) {
      const double t_rel = st * dinv[0] / sqrt(sn1);
      const double s_rel = dss[tid] * dinv[1] / sqrt(dsn2[tid]);
      sdiff[tid] = t_rel - s_rel;
      swout[tid] = expf((float)(so * (1.0 / (double)T_)));
    }
    __syncthreads();
    if (tid < 64) {
      // stable top-10: butterfly argmax under (value desc, index asc)
      const int l = tid;
      const double va = sdiff[l];
      const double vb = (l < P_ - 64) ? sdiff[l + 64] : -1.0e300;
      bool ta = false, tb = (l >= P_ - 64);
      int sel[P2_];
#pragma unroll
      for (int t = 0; t < P2_; ++t) {
        double cv; int cj;
        const bool aok = !ta, bok = !tb;
        if (aok && (!bok || va >= vb)) { cv = va; cj = l; }
        else if (bok)                  { cv = vb; cj = l + 64; }
        else                           { cv = -1.0e300; cj = 0x7fffffff; }
#pragma unroll
        for (int sh = 1; sh < 64; sh <<= 1) {
          const double ov = __shfl_xor(cv, sh);
          const int    oj = __shfl_xor(cj, sh);
          if (ov > cv || (ov == cv && oj < cj)) { cv = ov; cj = oj; }
        }
        sel[t] = cj;
        if (cj == l) ta = true;
        if (cj == l + 64) tb = true;
      }
      if (l == 0) {
        sel[0] = 0;  // .at[:,0].set(0) applied AFTER taking top-P2
        double sp = 0.0;
#pragma unroll
        for (int t = 0; t < P2_; ++t) {
          const float e = swout[sel[t]];
          wsel[b * P2_ + t] = e;  // unnormalized
          sp += (double)e;
        }
        wpart[GGATH_ + b] = sp;
      }
    }
  } else if (bid < GCOS_ + GCOPY_) {
    // ---- copy memory_v1 -> outmem, bin-aligned to the 2 MB slices ----
    // XCD r owns bins {r, r+8} = rows [r*4096,(r+1)*4096) U [(r+8)*4096, ...)
    const int g = bid - GCOS_;
    const int r = g & 7, q = g >> 3;                     // q in [0,256)
    const size_t row0 = (q < 128) ? ((size_t)r * 4096 + (size_t)q * 32)
                                  : ((size_t)(r + 8) * 4096 + (size_t)(q - 128) * 32);
    const size_t base = row0 * D_;                       // 32 rows = 16 KB
    const float4* __restrict__ s = reinterpret_cast<const float4*>(mem1 + base);
    float4* __restrict__ d = reinterpret_cast<float4*>(outmem + base);
#pragma unroll
    for (int i = 0; i < 4; ++i) d[i * 256 + tid] = s[i * 256 + tid];
  } else {
    // ---- binned gather dots: 16 lanes/row, 8 rows in flight, dense e out ----
    const int g = bid - GCOS_ - GCOPY_;
    const int bin = g & 15, b = g >> 4;
    const int count = counts[b * NBIN_ + bin];
    const unsigned* __restrict__ lb = lists + ((size_t)(b * NBIN_ + bin)) * SLOT_;
    float* __restrict__ eb = evals + ((size_t)(b * NBIN_ + bin)) * SLOT_;
    const int j = tid & 15, gg = tid >> 4;               // 16 groups of 16 lanes
    const float4* __restrict__ v2p = reinterpret_cast<const float4*>(v2 + (size_t)b * D_);
    const float4 x0 = v2p[j], x1 = v2p[j + 16];

    double de = 0.0;
    for (int s = gg; s < count; s += 128) {              // 8 rows deep per group
      unsigned en[8];
#pragma unroll
      for (int u = 0; u < 8; ++u) {
        const int p = s + u * 16;
        en[u] = lb[p < SLOT_ ? p : SLOT_ - 1];           // overread safe: row<=0xFFFF
      }
      float4 ra[8], rb[8];
#pragma unroll
      for (int u = 0; u < 8; ++u) {
        const float4* __restrict__ rp =
            reinterpret_cast<const float4*>(mem1 + (size_t)(en[u] & 0xFFFFu) * D_);
        ra[u] = rp[j];
        rb[u] = rp[j + 16];
      }
#pragma unroll
      for (int u = 0; u < 8; ++u) {
        float d = ra[u].x * x0.x + ra[u].y * x0.y + ra[u].z * x0.z + ra[u].w * x0.w
                + rb[u].x * x1.x + rb[u].y * x1.y + rb[u].z * x1.z + rb[u].w * x1.w;
#pragma unroll
        for (int sh = 1; sh < 16; sh <<= 1) d += __shfl_xor(d, sh);
        if (j == 0 && s + u * 16 < count) {
          const float f = expf(d * (1.0f / T_));
          eb[s + u * 16] = f;                            // dense per-(b,bin)
          de += (double)f;
        }
      }
    }
#pragma unroll
    for (int sh = 1; sh < 64; sh <<= 1) de += __shfl_xor(de, sh);
    if ((tid & 63) == 0) lacc[tid >> 6] = de;
    __syncthreads();
    if (tid == 0) wpart[g] = (lacc[0] + lacc[1]) + (lacc[2] + lacc[3]);
  }
}

// ---------------- kernel 2: reduce partials -> 1/Z ----------------
__global__ __launch_bounds__(256) void k_z(
    const double* __restrict__ wpart, float* __restrict__ invz)
{
  __shared__ double lds[4];
  const int tid = threadIdx.x;
  double s = 0.0;
  for (int i = tid; i < NPART_; i += 256) s += wpart[i];
#pragma unroll
  for (int sh = 1; sh < 64; sh <<= 1) s += __shfl_xor(s, sh);
  if ((tid & 63) == 0) lds[tid >> 6] = s;
  __syncthreads();
  if (tid == 0) {
    const double S = (lds[0] + lds[1]) + (lds[2] + lds[3]);
    const double Z = S / ((double)B_ * (double)OC_) * (double)N_;
    *invz = (float)(1.0 / Z);
  }
}

// -------- kernel 3: permute dense e -> out (scaled), + y-row update --------
__global__ __launch_bounds__(256) void k_out(
    const unsigned* __restrict__ lists, const int* __restrict__ counts,
    const float* __restrict__ evals, const float* __restrict__ wsel,
    const float* __restrict__ invz, const float* __restrict__ mem1,
    const float* __restrict__ v1, const int* __restrict__ y,
    float* __restrict__ out, float* __restrict__ outmem)
{
  __shared__ float srow[K_];  // 16 KB
  const int b = blockIdx.x;
  const int tid = threadIdx.x;
  const float sc = *invz;
#pragma unroll
  for (int bin = 0; bin < NBIN_; ++bin) {
    const int cnt = counts[b * NBIN_ + bin];
    const unsigned* __restrict__ lb = lists + ((size_t)(b * NBIN_ + bin)) * SLOT_;
    const float* __restrict__ eb = evals + ((size_t)(b * NBIN_ + bin)) * SLOT_;
    for (int s = tid; s < cnt; s += 256) srow[lb[s] >> 16] = eb[s];
  }
  __syncthreads();
  float* __restrict__ orow = out + (size_t)b * OC_;
  if (tid < P2_) orow[tid] = wsel[b * P2_ + tid] * sc;
  for (int i = tid; i < K_; i += 256) orow[P2_ + i] = srow[i] * sc;
  if (tid < 64) {
    // y-row momentum update + normalize (overwrites copied row)
    const int row = y[b];
    const float2 m = *reinterpret_cast<const float2*>(mem1 + (size_t)row * D_ + tid * 2);
    const float2 a = *reinterpret_cast<const float2*>(v1 + (size_t)b * D_ + tid * 2);
    float2 l;
    l.x = m.x * 0.5f + a.x * 0.5f;
    l.y = m.y * 0.5f + a.y * 0.5f;
    float n = l.x * l.x + l.y * l.y;
#pragma unroll
    for (int sh = 1; sh < 64; sh <<= 1) n += __shfl_xor(n, sh);
    const float inv = 1.0f / sqrtf(n);
    float2 o;
    o.x = l.x * inv;
    o.y = l.y * inv;
    *reinterpret_cast<float2*>(outmem + (size_t)row * D_ + tid * 2) = o;
  }
}

extern "C" void kernel_launch(void* const* d_in, const int* in_sizes, int n_in,
                              void* d_out, int out_size, void* d_ws, size_t ws_size,
                              hipStream_t stream) {
  // setup_inputs order: epoch, v1, v2, y, idx, memory_v1, memory_v2
  const float* v1   = (const float*)d_in[1];
  const float* v2   = (const float*)d_in[2];
  const int*   y    = (const int*)d_in[3];
  const int*   idx  = (const int*)d_in[4];
  const float* mem1 = (const float*)d_in[5];
  const float* mem2 = (const float*)d_in[6];

  float* out    = (float*)d_out;                      // (B, P2+K) scores
  float* outmem = out + (size_t)B_ * OC_;             // (N, D) new memory

  char* ws = (char*)d_ws;
  constexpr size_t LSZ = (size_t)B_ * NBIN_ * SLOT_ * 4;         // 6,291,456 B
  double*   wpart  = (double*)ws;                                // NPART_ doubles (34,816 B)
  int*      counts = (int*)(ws + 40960);                         // B*16 ints (16,384 B)
  unsigned* lists  = (unsigned*)(ws + 65536);                    // LSZ bytes
  float*    evals  = (float*)(ws + 65536 + LSZ);                 // LSZ bytes
  float*    wsel   = (float*)(ws + 65536 + 2 * LSZ);             // B*P2 floats
  float*    invz   = (float*)(ws + 65536 + 2 * LSZ + 16384);

  k_bin<<<B_, 256, 0, stream>>>(idx, lists, counts);
  k_main<<<GCOS_ + GCOPY_ + GGATH_, 256, 0, stream>>>(
      v1, v2, idx, mem1, mem2, lists, counts, evals, wsel, outmem, wpart);
  k_z<<<1, 256, 0, stream>>>(wpart, invz);
  k_out<<<B_, 256, 0, stream>>>(lists, counts, evals, wsel, invz,
                                mem1, v1, y, out, outmem);
}